// Round 10
// baseline (1677.096 us; speedup 1.0000x reference)
//
#include <hip/hip_runtime.h>

#define T_TOKENS 32768
#define DIMK     2048
#define NEXP     64
#define KC       32
#define NCHUNK   (DIMK / KC)   // 64
#define TPB      512           // 8 waves: 2 waves/SIMD for latency hiding
#define TOKB     128
#define EPW      8             // experts per wave
#define HSTR     130           // h_lds [KC][HSTR] transposed (+2 pad)
#define WSTR     32            // w_lds [NEXP][WSTR] natural, 128B rows
#define HBUF     (KC * HSTR)   // 4160 floats
#define WBUF     (NEXP * WSTR) // 2048 floats
#define BUFSZ    (HBUF + WBUF) // 6208 floats
#define LTSTR    68            // epilogue tile stride

__global__ __launch_bounds__(TPB) void router_kernel(
    const float* __restrict__ hs, const float* __restrict__ wt,
    float* __restrict__ logits, float* __restrict__ tkp, float* __restrict__ tki)
{
    __shared__ float smem[2 * BUFSZ];   // 49,664 B

    const int tid  = threadIdx.x;
    const int lane = tid & 63;
    const int wv   = tid >> 6;          // 0..7
    const int ebase = wv * EPW;         // wave's 8 experts
    const int t0   = blockIdx.x * TOKB;

    float acc0[EPW], acc1[EPW];         // 2 tokens x 8 experts
#pragma unroll
    for (int i = 0; i < EPW; ++i) { acc0[i] = 0.f; acc1[i] = 0.f; }

    // staging decomposition (fixed per thread): h = 1024 float4, w = 512 float4
    const int htok0 = tid >> 3,          hk40 = tid & 7;          // f = tid
    const int htok1 = (512 + tid) >> 3,  hk41 = tid & 7;          // f = 512+tid (same &7)
    const int we0   = tid >> 3,          wk40 = tid & 7;

    float4 ph0, ph1, pw0;

    // ---- prestage chunk 0 into buffer 0 ----
    ph0 = *(const float4*)(hs + (size_t)(t0 + htok0) * DIMK + hk40 * 4);
    ph1 = *(const float4*)(hs + (size_t)(t0 + htok1) * DIMK + hk41 * 4);
    pw0 = *(const float4*)(wt + (size_t)we0 * DIMK + wk40 * 4);
    {
        float* bh = smem;
        float* bw = smem + HBUF;
        bh[(hk40*4+0)*HSTR + htok0] = ph0.x; bh[(hk40*4+1)*HSTR + htok0] = ph0.y;
        bh[(hk40*4+2)*HSTR + htok0] = ph0.z; bh[(hk40*4+3)*HSTR + htok0] = ph0.w;
        bh[(hk41*4+0)*HSTR + htok1] = ph1.x; bh[(hk41*4+1)*HSTR + htok1] = ph1.y;
        bh[(hk41*4+2)*HSTR + htok1] = ph1.z; bh[(hk41*4+3)*HSTR + htok1] = ph1.w;
        *(float4*)&bw[we0*WSTR + wk40*4] = pw0;
    }
    __syncthreads();

#pragma unroll 1
    for (int kc = 0; kc < NCHUNK; ++kc) {
        const int buf = kc & 1;
        const float* bh = smem + buf * BUFSZ;
        const float* bw = bh + HBUF;

        // issue next-chunk global loads first (latency hides under FMA block)
        if (kc + 1 < NCHUNK) {
            const int kb = (kc + 1) * KC;
            ph0 = *(const float4*)(hs + (size_t)(t0 + htok0) * DIMK + kb + hk40 * 4);
            ph1 = *(const float4*)(hs + (size_t)(t0 + htok1) * DIMK + kb + hk41 * 4);
            pw0 = *(const float4*)(wt + (size_t)we0 * DIMK + kb + wk40 * 4);
        }

        // compute: 8 k4-groups x (2 tok x 8 exp x 4 k) = 512 FMA/thread/chunk
#pragma unroll
        for (int k4 = 0; k4 < 8; ++k4) {
            float2 h0 = *(const float2*)&bh[(k4*4+0)*HSTR + 2*lane];
            float2 h1 = *(const float2*)&bh[(k4*4+1)*HSTR + 2*lane];
            float2 h2 = *(const float2*)&bh[(k4*4+2)*HSTR + 2*lane];
            float2 h3 = *(const float2*)&bh[(k4*4+3)*HSTR + 2*lane];
#pragma unroll
            for (int e = 0; e < EPW; ++e) {
                float4 w4 = *(const float4*)&bw[(ebase + e)*WSTR + k4*4]; // wave-uniform broadcast
                acc0[e] = fmaf(h0.x, w4.x, acc0[e]);
                acc0[e] = fmaf(h1.x, w4.y, acc0[e]);
                acc0[e] = fmaf(h2.x, w4.z, acc0[e]);
                acc0[e] = fmaf(h3.x, w4.w, acc0[e]);
                acc1[e] = fmaf(h0.y, w4.x, acc1[e]);
                acc1[e] = fmaf(h1.y, w4.y, acc1[e]);
                acc1[e] = fmaf(h2.y, w4.z, acc1[e]);
                acc1[e] = fmaf(h3.y, w4.w, acc1[e]);
            }
        }

        // write prefetched regs to the other buffer
        if (kc + 1 < NCHUNK) {
            float* nh = smem + (buf ^ 1) * BUFSZ;
            float* nw = nh + HBUF;
            nh[(hk40*4+0)*HSTR + htok0] = ph0.x; nh[(hk40*4+1)*HSTR + htok0] = ph0.y;
            nh[(hk40*4+2)*HSTR + htok0] = ph0.z; nh[(hk40*4+3)*HSTR + htok0] = ph0.w;
            nh[(hk41*4+0)*HSTR + htok1] = ph1.x; nh[(hk41*4+1)*HSTR + htok1] = ph1.y;
            nh[(hk41*4+2)*HSTR + htok1] = ph1.z; nh[(hk41*4+3)*HSTR + htok1] = ph1.w;
            *(float4*)&nw[we0*WSTR + wk40*4] = pw0;
        }
        __syncthreads();
    }

    // ---- epilogue: logits out + LDS tile for top-2 ----
    float* tile = smem;                 // [128][LTSTR] = 34,816 B, fits
    const int tA = 2*lane, tB = 2*lane + 1;
#pragma unroll
    for (int i = 0; i < 2; ++i) {       // 8 experts = 2 float4 per token
        *(float4*)(logits + (size_t)(t0 + tA) * NEXP + ebase + i*4) =
            make_float4(acc0[i*4+0], acc0[i*4+1], acc0[i*4+2], acc0[i*4+3]);
        *(float4*)(logits + (size_t)(t0 + tB) * NEXP + ebase + i*4) =
            make_float4(acc1[i*4+0], acc1[i*4+1], acc1[i*4+2], acc1[i*4+3]);
    }
#pragma unroll
    for (int i = 0; i < EPW; ++i) {
        tile[tA*LTSTR + ebase + i] = acc0[i];
        tile[tB*LTSTR + ebase + i] = acc1[i];
    }
    __syncthreads();

    if (tid < TOKB) {
        const int t = tid;
        float m1 = -1e30f; int i1 = 0;
#pragma unroll
        for (int e = 0; e < NEXP; ++e) {
            float v = tile[t*LTSTR + e];
            if (v > m1) { m1 = v; i1 = e; }   // strict > keeps earliest index (stable)
        }
        float m2 = -1e30f; int i2 = 0;
#pragma unroll
        for (int e = 0; e < NEXP; ++e) {
            float v = tile[t*LTSTR + e];
            if (e != i1 && v > m2) { m2 = v; i2 = e; }
        }
        float e2v = __expf(m2 - m1);
        float s = 1.f + e2v;
        tkp[(size_t)(t0 + t) * 2 + 0] = 1.f / s;
        tkp[(size_t)(t0 + t) * 2 + 1] = e2v / s;
        // harness reads concatenated d_out as float32 -> indices stored as float
        tki[(size_t)(t0 + t) * 2 + 0] = (float)i1;
        tki[(size_t)(t0 + t) * 2 + 1] = (float)i2;
    }
}

extern "C" void kernel_launch(void* const* d_in, const int* in_sizes, int n_in,
                              void* d_out, int out_size, void* d_ws, size_t ws_size,
                              hipStream_t stream) {
    const float* hs = (const float*)d_in[0];
    const float* wt = (const float*)d_in[1];
    float* logits = (float*)d_out;
    float* tkp    = logits + (size_t)T_TOKENS * NEXP;
    float* tki    = tkp + (size_t)T_TOKENS * 2;

    dim3 grid(T_TOKENS / TOKB);   // 256 blocks = 1 per CU, 8 waves each
    router_kernel<<<grid, TPB, 0, stream>>>(hs, wt, logits, tkp, tki);
}